// Round 9
// baseline (149.557 us; speedup 1.0000x reference)
//
#include <hip/hip_runtime.h>

typedef __bf16 bf16x8 __attribute__((ext_vector_type(8)));
typedef float f32x4 __attribute__((ext_vector_type(4)));
typedef unsigned short u16x8 __attribute__((ext_vector_type(8)));

typedef const void __attribute__((address_space(1)))* gas_ptr;
typedef void __attribute__((address_space(3)))* las_ptr;

#define GLOAD16(gp, lp) __builtin_amdgcn_global_load_lds((gas_ptr)(gp), (las_ptr)(lp), 16, 0, 0)

__device__ __forceinline__ unsigned short f2bf(float f) {
  unsigned int u = __float_as_uint(f);
  u += 0x7FFF + ((u >> 16) & 1);
  return (unsigned short)(u >> 16);
}
__device__ __forceinline__ float bf2f(unsigned short u) {
  return __uint_as_float(((unsigned int)u) << 16);
}

// ---------------- prep: W2 [512][4000] f32 -> W2T [4096][512] bf16 (zero-padded) ----------------
__global__ __launch_bounds__(256) void k_w2t(const float* __restrict__ W2,
                                             unsigned short* __restrict__ W2T) {
  __shared__ float tile[64][65];
  const int gt = blockIdx.x;
  const int jt = blockIdx.y;
  const int t = threadIdx.x;
  const int c = t & 63, r4 = t >> 6;
#pragma unroll
  for (int r = 0; r < 16; ++r) {
    int jj = r * 4 + r4;
    int g = gt * 64 + c;
    tile[jj][c] = (g < 4000) ? W2[(size_t)(jt * 64 + jj) * 4000 + g] : 0.f;
  }
  __syncthreads();
#pragma unroll
  for (int r = 0; r < 16; ++r) {
    int gg = r * 4 + r4;
    W2T[(size_t)(gt * 64 + gg) * 512 + jt * 64 + c] = f2bf(tile[c][gg]);
  }
}

// ---------------- fused prep: mask + Hb + Astack, one sample per WG ----------------
__global__ __launch_bounds__(256) void k_maskprep(const float* __restrict__ z,
                                                  const float* __restrict__ W1,
                                                  const float* __restrict__ b1,
                                                  unsigned short* __restrict__ Hb,
                                                  unsigned short* __restrict__ Astack) {
  __shared__ float zs[32];
  __shared__ __align__(8) unsigned char mk[512];
  const int b = blockIdx.x, t = threadIdx.x;
  if (t < 32) zs[t] = z[b * 32 + t];
  __syncthreads();
#pragma unroll
  for (int jj = 0; jj < 2; ++jj) {
    int j = t + jj * 256;
    float a = b1[j];
#pragma unroll
    for (int i = 0; i < 32; ++i) a = fmaf(zs[i], W1[i * 512 + j], a);
    bool m = a > 0.f;
    mk[j] = m ? 1 : 0;
    Hb[b * 512 + j] = m ? f2bf(a) : (unsigned short)0;
  }
  __syncthreads();
#pragma unroll
  for (int k = 0; k < 8; ++k) {
    int c8 = t + k * 256;
    int row = c8 >> 6;
    int k8 = (c8 & 63) * 8;
    unsigned long long m8 = *(const unsigned long long*)(mk + k8);
    const float* w = W1 + row * 512 + k8;
    u16x8 out;
#pragma unroll
    for (int e = 0; e < 8; ++e)
      out[e] = ((m8 >> (e * 8)) & 0xffULL) ? f2bf(w[e]) : (unsigned short)0;
    *(u16x8*)(Astack + ((size_t)(b * 32 + row)) * 512 + k8) = out;
  }
}

// ---------------- main GEMM: 256x256 tile, BK=64, fused S + Gram epilogue ----------------
// grid (32 M-tiles = 8 samples, 16 N-tiles = 256 genes), 512 threads = 8 waves (2M x 4N)
// LDS: dbuf 2*65536 (A 256x64 swz + B 256x64 swz per buf); c_lds @131072 (8KB); H_lds @139264 (16KB)
__global__ __launch_bounds__(512, 2) void k_gemm(const unsigned short* __restrict__ Astack,
                                                 const unsigned short* __restrict__ W2T,
                                                 const unsigned short* __restrict__ Hb,
                                                 const float* __restrict__ b2,
                                                 const float* __restrict__ log_theta,
                                                 float* __restrict__ Gram) {
  extern __shared__ __align__(16) char smem[];

  const int bm = blockIdx.x;
  const int g0 = blockIdx.y * 256;
  const int t = threadIdx.x;
  const int lane = t & 63;
  const int wave = t >> 6;           // 0..7
  const int wm = wave >> 2;          // 0..1 : 128-row half
  const int wn = wave & 3;           // 0..3 : 64-col quarter
  const int trow = t >> 3;           // 0..63
  const int kxor = (((t & 7) ^ (trow & 7)) << 3);
  const int c16 = lane & 15;
  const int lg = lane >> 4;

  f32x4 acc[8][4];
#pragma unroll
  for (int mt = 0; mt < 8; ++mt)
#pragma unroll
    for (int nt = 0; nt < 4; ++nt) acc[mt][nt] = (f32x4){0.f, 0.f, 0.f, 0.f};
  f32x4 sacc[4];
#pragma unroll
  for (int nt = 0; nt < 4; ++nt) sacc[nt] = (f32x4){0.f, 0.f, 0.f, 0.f};

  const unsigned short* Aptr = Astack + (size_t)bm * 256 * 512;
  const unsigned short* Bptr = W2T + (size_t)g0 * 512;
  char* H_lds = smem + 139264;       // [16][512] bf16, swizzled; rows 8..15 zero

#define STAGE_BIG(buf, kt)                                                            \
  do {                                                                                \
    _Pragma("unroll") for (int q = 0; q < 4; ++q)                                     \
      GLOAD16(Aptr + (size_t)(q * 64 + trow) * 512 + (kt) * 64 + kxor,                \
              smem + (buf) * 65536 + q * 8192 + wave * 1024);                         \
    _Pragma("unroll") for (int q = 0; q < 4; ++q)                                     \
      GLOAD16(Bptr + (size_t)(q * 64 + trow) * 512 + (kt) * 64 + kxor,                \
              smem + (buf) * 65536 + 32768 + q * 8192 + wave * 1024);                 \
  } while (0)

  STAGE_BIG(0, 0);

  // stage H rows (8 real + 8 zero-pad) into swizzled H_lds
#pragma unroll
  for (int i = 0; i < 2; ++i) {
    int o = t * 2 + i;             // 0..1023, 16B each
    int row = o >> 6;              // 0..15
    int col8 = (o & 63) * 8;
    u16x8 v;
    if (row < 8) {
      v = *(const u16x8*)(Hb + (size_t)(bm * 8 + row) * 512 + col8);
    } else {
#pragma unroll
      for (int e = 0; e < 8; ++e) v[e] = 0;
    }
    *(u16x8*)(H_lds + row * 1024 + ((col8 * 2) ^ ((row & 7) << 4))) = v;
  }
  __syncthreads();

  for (int kt = 0; kt < 8; ++kt) {
    int cur = kt & 1;
    if (kt < 7) STAGE_BIG(cur ^ 1, kt + 1);
    const char* Ab = smem + cur * 65536;
    const char* Bb = smem + cur * 65536 + 32768;
#pragma unroll
    for (int ks = 0; ks < 2; ++ks) {
      int kb = ks * 64 + lg * 16;
      bf16x8 av[8], bv[4];
#pragma unroll
      for (int mt = 0; mt < 8; ++mt) {
        int row = wm * 128 + mt * 16 + c16;
        av[mt] = *(const bf16x8*)(Ab + row * 128 + (kb ^ ((row & 7) << 4)));
      }
#pragma unroll
      for (int nt = 0; nt < 4; ++nt) {
        int row = wn * 64 + nt * 16 + c16;
        bv[nt] = *(const bf16x8*)(Bb + row * 128 + (kb ^ ((row & 7) << 4)));
      }
#pragma unroll
      for (int mt = 0; mt < 8; ++mt)
#pragma unroll
        for (int nt = 0; nt < 4; ++nt)
          acc[mt][nt] = __builtin_amdgcn_mfma_f32_16x16x32_bf16(av[mt], bv[nt], acc[mt][nt], 0, 0, 0);
      if (wm == 0) {
        // fused S = H @ W2T^T : reuse bv, A-frag from H_lds
        bf16x8 hv = *(const bf16x8*)(H_lds + c16 * 1024 +
                                     (((kt * 64 + ks * 32 + lg * 8) * 2) ^ ((c16 & 7) << 4)));
#pragma unroll
        for (int nt = 0; nt < 4; ++nt)
          sacc[nt] = __builtin_amdgcn_mfma_f32_16x16x32_bf16(hv, bv[nt], sacc[nt], 0, 0, 0);
      }
    }
    __syncthreads();
  }

  // ---- epilogue: T tile (bf16, swizzled) -> LDS [256][256]; c from sacc -> c_lds ----
  float* c_lds = (float*)(smem + 131072);   // [8][256]

#pragma unroll
  for (int mt = 0; mt < 8; ++mt)
#pragma unroll
    for (int nt = 0; nt < 4; ++nt)
#pragma unroll
      for (int r = 0; r < 4; ++r) {
        int row = wm * 128 + mt * 16 + lg * 4 + r;
        int col = wn * 64 + nt * 16 + c16;
        *(unsigned short*)(smem + row * 512 + ((col * 2) ^ ((row & 7) << 4))) = f2bf(acc[mt][nt][r]);
      }

  if (wm == 0) {
#pragma unroll
    for (int nt = 0; nt < 4; ++nt) {
      int col = wn * 64 + nt * 16 + c16;
      int gg = g0 + col;
      float bb = (gg < 4000) ? b2[gg] : 0.f;
      float th = (gg < 4000) ? expf(log_theta[gg]) : 1.f;
#pragma unroll
      for (int r = 0; r < 4; ++r) {
        int srow = lg * 4 + r;
        if (srow < 8) {
          float s = sacc[nt][r] + bb;
          float sig = 1.f / (1.f + expf(-s));
          float mu = (s > 20.f) ? s : log1pf(expf(s));
          float w = th / (mu * (mu + th) + 1e-6f);
          c_lds[srow * 256 + col] = (gg < 4000) ? (w * sig * sig) : 0.f;
        }
      }
    }
  }
  __syncthreads();

  // ---- Gram via MFMA: wave s owns sample s; 32x32 over 256 genes ----
  {
    const int s = wave;
    f32x4 gacc[2][2];
#pragma unroll
    for (int m2 = 0; m2 < 2; ++m2)
#pragma unroll
      for (int n2 = 0; n2 < 2; ++n2) gacc[m2][n2] = (f32x4){0.f, 0.f, 0.f, 0.f};

#pragma unroll
    for (int ch = 0; ch < 8; ++ch) {
      f32x4 cv0 = *(const f32x4*)(c_lds + s * 256 + ch * 32 + lg * 8);
      f32x4 cv1 = *(const f32x4*)(c_lds + s * 256 + ch * 32 + lg * 8 + 4);
      u16x8 raw[2];
      bf16x8 ap[2], bp[2];
#pragma unroll
      for (int m2 = 0; m2 < 2; ++m2) {
        int row = s * 32 + m2 * 16 + c16;
        raw[m2] = *(const u16x8*)(smem + row * 512 + ((ch * 64 + lg * 16) ^ ((row & 7) << 4)));
        u16x8 sc;
#pragma unroll
        for (int e = 0; e < 4; ++e) sc[e] = f2bf(bf2f(raw[m2][e]) * cv0[e]);
#pragma unroll
        for (int e = 0; e < 4; ++e) sc[4 + e] = f2bf(bf2f(raw[m2][4 + e]) * cv1[e]);
        ap[m2] = __builtin_bit_cast(bf16x8, sc);
        bp[m2] = __builtin_bit_cast(bf16x8, raw[m2]);
      }
#pragma unroll
      for (int m2 = 0; m2 < 2; ++m2)
#pragma unroll
        for (int n2 = 0; n2 < 2; ++n2)
          gacc[m2][n2] = __builtin_amdgcn_mfma_f32_16x16x32_bf16(ap[m2], bp[n2], gacc[m2][n2], 0, 0, 0);
    }

#pragma unroll
    for (int m2 = 0; m2 < 2; ++m2)
#pragma unroll
      for (int n2 = 0; n2 < 2; ++n2)
#pragma unroll
        for (int r = 0; r < 4; ++r) {
          int i = m2 * 16 + lg * 4 + r;
          int j = n2 * 16 + c16;
          atomicAdd(Gram + (size_t)(bm * 8 + s) * 1024 + i * 32 + j, gacc[m2][n2][r]);
        }
  }
}

// ---------------- loss reduce ----------------
__global__ __launch_bounds__(256) void k_loss(const float* __restrict__ Gram,
                                              float* __restrict__ out) {
  __shared__ float red[4];
  const int b = blockIdx.x, t = threadIdx.x;
  float local = 0.f;
#pragma unroll
  for (int k = 0; k < 4; ++k) {
    int e = t + k * 256;
    float d = Gram[(size_t)b * 1024 + e] - (((e >> 5) == (e & 31)) ? 1.f : 0.f);
    local += d * d;
  }
#pragma unroll
  for (int off = 32; off > 0; off >>= 1) local += __shfl_down(local, off);
  if ((t & 63) == 0) red[t >> 6] = local;
  __syncthreads();
  if (t == 0) {
    float s = red[0] + red[1] + red[2] + red[3];
    atomicAdd(out, s * (1.f / 256.f));
  }
}

extern "C" void kernel_launch(void* const* d_in, const int* in_sizes, int n_in,
                              void* d_out, int out_size, void* d_ws, size_t ws_size,
                              hipStream_t stream) {
  const float* z = (const float*)d_in[0];
  const float* W1 = (const float*)d_in[1];
  const float* b1 = (const float*)d_in[2];
  const float* W2 = (const float*)d_in[3];
  const float* b2 = (const float*)d_in[4];
  const float* lt = (const float*)d_in[5];

  char* ws = (char*)d_ws;
  unsigned short* W2T = (unsigned short*)ws;                   // 4,194,304
  unsigned short* Astack = (unsigned short*)(ws + 4194304);    // 8,388,608
  unsigned short* Hb = (unsigned short*)(ws + 12582912);       // 262,144
  float* Gram = (float*)(ws + 17170432);                       // 1,048,576

  hipMemsetAsync(Gram, 0, 256 * 1024 * 4, stream);
  hipMemsetAsync(d_out, 0, 4, stream);

  static const int kGemmLds = 139264 + 16384;   // dbuf 128K + c_lds 8K + H_lds 16K
  hipFuncSetAttribute((const void*)k_gemm, hipFuncAttributeMaxDynamicSharedMemorySize, kGemmLds);

  k_w2t<<<dim3(64, 8), 256, 0, stream>>>(W2, W2T);
  k_maskprep<<<256, 256, 0, stream>>>(z, W1, b1, Hb, Astack);
  k_gemm<<<dim3(32, 16), 512, kGemmLds, stream>>>(Astack, W2T, Hb, b2, lt, Gram);
  k_loss<<<256, 256, 0, stream>>>(Gram, (float*)d_out);
}